// Round 5
// baseline (195.074 us; speedup 1.0000x reference)
//
#include <hip/hip_runtime.h>

#define N_PTS   128
#define EPS_F   1e-10f
#define FAR_F   1e10f
#define PAIR_B  5120                     // LDS bytes per ray-pair buffer
// gfx9 waitcnt simm16: vmcnt[3:0] | expcnt<<4 | lgkmcnt<<8 | vmcnt[5:4]<<14
#define WAITCNT_VM(n) (0x0F70 | (n))     // expcnt/lgkmcnt = no-wait, vmcnt = n

typedef const __attribute__((address_space(1))) unsigned int* gptr_t;
typedef __attribute__((address_space(3))) unsigned int* lptr_t;

// DPP ctrl: ROW_SHR1/2/4/8=0x111/2/4/8, ROW_BCAST15=0x142,
//           WAVE_SHL1=0x130, WAVE_SHR1=0x138
template<int CTRL, int ROW_MASK>
__device__ __forceinline__ float dpp_mov(float src, float old) {
    union { float f; int i; } s, o, r;
    s.f = src; o.f = old;
    r.i = __builtin_amdgcn_update_dpp(o.i, s.i, CTRL, ROW_MASK, 0xF, false);
    return r.f;
}

// Sum over each 32-lane half-wave; totals land in lanes 31 and 63.
__device__ __forceinline__ float half32_reduce_add(float x) {
    x += dpp_mov<0x111, 0xF>(x, 0.0f);
    x += dpp_mov<0x112, 0xF>(x, 0.0f);
    x += dpp_mov<0x114, 0xF>(x, 0.0f);
    x += dpp_mov<0x118, 0xF>(x, 0.0f);
    x += dpp_mov<0x142, 0xA>(x, 0.0f);   // row_bcast15 -> rows 1,3
    return x;
}

// Stage one ray-pair (5 KB) into this wave's LDS buffer via async DMA.
// Layout: [0,1KB) density pair | [1KB,2KB) depth pair | [2KB,5KB) feature pair.
// LDS dest is wave-uniform base; HW scatters lane i to base + 16*i.
__device__ __forceinline__ void stage_pair(const char* density, const char* feature,
                                           const char* depth, long long p,
                                           char* buf, int lane) {
    const long long lo = (long long)lane * 16;
    __builtin_amdgcn_global_load_lds((gptr_t)(density + p * 1024 + lo),        (lptr_t)(buf       ), 16, 0, 0);
    __builtin_amdgcn_global_load_lds((gptr_t)(depth   + p * 1024 + lo),        (lptr_t)(buf + 1024), 16, 0, 0);
    __builtin_amdgcn_global_load_lds((gptr_t)(feature + p * 3072 + lo),        (lptr_t)(buf + 2048), 16, 0, 0);
    __builtin_amdgcn_global_load_lds((gptr_t)(feature + p * 3072 + 1024 + lo), (lptr_t)(buf + 3072), 16, 0, 0);
    __builtin_amdgcn_global_load_lds((gptr_t)(feature + p * 3072 + 2048 + lo), (lptr_t)(buf + 4096), 16, 0, 0);
}

// Persistent; half-wave per ray (lane owns 4 points). All global reads go
// through the global_load_lds DMA path, double-buffered per wave with
// per-wave s_waitcnt vmcnt(5) sync — no __syncthreads, prefetch loads stay
// in flight across iterations.
__global__ __launch_bounds__(256) void volrend_kernel(
        const float* __restrict__ density,
        const float* __restrict__ feature,
        const float* __restrict__ depth,
        float* __restrict__ out, int n_rays) {
    __shared__ char lds_raw[4 * 2 * PAIR_B];          // 4 waves x 2 bufs x 5KB
    const int lane = threadIdx.x & 63;
    const int hl   = lane & 31;                       // lane within half-wave
    const int half = lane >> 5;                       // which ray of the pair
    const int wid  = threadIdx.x >> 6;
    char* const wbase = lds_raw + wid * (2 * PAIR_B);

    const int wave0  = (blockIdx.x * blockDim.x + threadIdx.x) >> 6;
    const int nwaves = (gridDim.x * blockDim.x) >> 6;
    const int npairs = n_rays >> 1;

    const char* dsrc = (const char*)density;
    const char* fsrc = (const char*)feature;
    const char* zsrc = (const char*)depth;

    int p = wave0;
    if (p >= npairs) return;

    char* cur = wbase;
    char* nxt = wbase + PAIR_B;
    stage_pair(dsrc, fsrc, zsrc, p, cur, lane);

    while (true) {
        const int pn = p + nwaves;                    // wave-uniform
        const bool have_next = (pn < npairs);
        if (have_next) {
            stage_pair(dsrc, fsrc, zsrc, pn, nxt, lane);
            __builtin_amdgcn_sched_barrier(0);
            __builtin_amdgcn_s_waitcnt(WAITCNT_VM(5));  // cur's 5 DMAs done
            __builtin_amdgcn_sched_barrier(0);
        } else {
            __builtin_amdgcn_sched_barrier(0);
            __builtin_amdgcn_s_waitcnt(WAITCNT_VM(0));
            __builtin_amdgcn_sched_barrier(0);
        }

        // ---- compute current pair from LDS ----
        const float4 dns = *(const float4*)(cur        + half * 512  + hl * 16);
        const float4 z   = *(const float4*)(cur + 1024 + half * 512  + hl * 16);
        const char*  fpb = cur + 2048 + half * 1536 + hl * 48;
        const float4 fa  = *(const float4*)(fpb);
        const float4 fb  = *(const float4*)(fpb + 16);
        const float4 fc  = *(const float4*)(fpb + 32);

        float nz = dpp_mov<0x130, 0xF>(z.x, 0.0f);    // wave_shl1: lane i <- i+1
        float d0 = z.y - z.x;
        float d1 = z.z - z.y;
        float d2 = z.w - z.z;
        float d3 = (hl == 31) ? FAR_F : (nz - z.w);

        float e0 = __expf(-d0 * dns.x), e1 = __expf(-d1 * dns.y);
        float e2 = __expf(-d2 * dns.z), e3 = __expf(-d3 * dns.w);
        float f0 = e0 + EPS_F, f1 = e1 + EPS_F, f2 = e2 + EPS_F, f3 = e3 + EPS_F;
        float a0 = 1.0f - e0,  a1 = 1.0f - e1,  a2 = 1.0f - e2,  a3 = 1.0f - e3;

        float pr = (f0 * f1) * (f2 * f3);
        pr *= dpp_mov<0x111, 0xF>(pr, 1.0f);
        pr *= dpp_mov<0x112, 0xF>(pr, 1.0f);
        pr *= dpp_mov<0x114, 0xF>(pr, 1.0f);
        pr *= dpp_mov<0x118, 0xF>(pr, 1.0f);
        pr *= dpp_mov<0x142, 0xA>(pr, 1.0f);          // row_bcast15 -> rows 1,3
        float T0 = dpp_mov<0x138, 0xF>(pr, 1.0f);     // wave_shr1 (exclusive)
        T0 = (hl == 0) ? 1.0f : T0;

        float w0 = T0 * a0; float T1 = T0 * f0;
        float w1 = T1 * a1; float T2 = T1 * f1;
        float w2 = T2 * a2; float T3 = T2 * f2;
        float w3 = T3 * a3;

        float rx = half32_reduce_add(w0 * fa.x + w1 * fa.w + w2 * fb.z + w3 * fc.y);
        float ry = half32_reduce_add(w0 * fa.y + w1 * fb.x + w2 * fb.w + w3 * fc.z);
        float rz = half32_reduce_add(w0 * fa.z + w1 * fb.y + w2 * fc.x + w3 * fc.w);
        float dd = half32_reduce_add(w0 * z.x  + w1 * z.y  + w2 * z.z  + w3 * z.w);

        const int ray = p * 2 + half;
        if (hl == 31) {                               // lanes 31/63: ray totals
            float* o  = out + (size_t)ray * 3;
            o[0] = rx; o[1] = ry; o[2] = rz;
            float* od = out + (size_t)n_rays * 3 + (size_t)ray * 3;
            od[0] = dd; od[1] = dd; od[2] = dd;
        }
        // ---------------------------------------

        if (!have_next) break;
        p = pn;
        char* t = cur; cur = nxt; nxt = t;
    }
}

extern "C" void kernel_launch(void* const* d_in, const int* in_sizes, int n_in,
                              void* d_out, int out_size, void* d_ws, size_t ws_size,
                              hipStream_t stream) {
    const float* density = (const float*)d_in[0];
    const float* feature = (const float*)d_in[1];
    const float* depth   = (const float*)d_in[2];
    float* out = (float*)d_out;
    const int n_rays = in_sizes[0] / N_PTS;           // 65536
    // 40 KB LDS/block -> 4 blocks/CU; 1024 blocks = 4096 waves, 8 pairs/wave.
    const int blocks = 1024;
    volrend_kernel<<<blocks, 256, 0, stream>>>(density, feature, depth, out, n_rays);
}